// Round 3
// baseline (426.222 us; speedup 1.0000x reference)
//
#include <hip/hip_runtime.h>

#define FNUM 40
#define DIM  64
#define NPAIR 780           // 40*39/2
#define BLOCK 256
#define IN4   (FNUM * DIM / 4)    // 640 float4 per batch row
#define OUT4  (NPAIR * DIM / 4)   // 12480 float4 per batch row
#define ROW4  17                  // padded LDS row stride in float4 (16 data + 1 pad)
#define ROWF  (ROW4 * 4)          // 68 floats

typedef float f32x4 __attribute__((ext_vector_type(4)));

__global__ __launch_bounds__(BLOCK)
void bilinear_fused(const float* __restrict__ in,
                    const float* __restrict__ w,
                    float* __restrict__ out)
{
    __shared__ float sIn[FNUM * ROWF];   // 10.88 KB (padded rows: +4-bank rotation/row)
    __shared__ float sXW[FNUM * ROWF];   // 10.88 KB

    const int tid  = threadIdx.x;
    const int b    = blockIdx.x;
    const int lane = tid & 63;
    const int wv   = tid >> 6;

    // ---- stage inputs[b] into padded LDS (global read stays linear/coalesced) ----
    const f32x4* in4 = (const f32x4*)in + (size_t)b * IN4;
    f32x4* sIn4 = (f32x4*)sIn;
    for (int k = tid; k < IN4; k += BLOCK)
        sIn4[(k >> 4) * ROW4 + (k & 15)] = in4[k];

    // ---- W column `lane` into registers ----
    float wcol[DIM];
    #pragma unroll
    for (int d = 0; d < DIM; ++d) wcol[d] = w[d * DIM + lane];

    __syncthreads();

    // ---- GEMM: wave wv computes rows wv*10 .. wv*10+9 (unchanged arithmetic) ----
    for (int r = 0; r < 10; ++r) {
        int f = wv * 10 + r;
        float rin = sIn[f * ROWF + lane];   // lane d holds in[f][d]
        float acc = 0.f;
        #pragma unroll
        for (int d = 0; d < DIM; ++d) {
            float bv = __uint_as_float(
                __builtin_amdgcn_readlane(__float_as_uint(rin), d));
            acc = fmaf(bv, wcol[d], acc);
        }
        sXW[f * ROWF + lane] = acc;
    }

    __syncthreads();

    // ---- pair phase: out[b, p*64 + d] = xw[i_p][d] * in[j_p][d] ----
    // (i,j) closed-form from p (no LDS index tables, iterations independent);
    // padded rows -> conflict-free ds_read_b128; unroll 8 -> batched loads ahead of stores.
    const f32x4* sXW4 = (const f32x4*)sXW;
    f32x4* out4 = (f32x4*)out + (size_t)b * OUT4;

    const int q  = tid & 15;
    const int p0 = tid >> 4;           // p advances by 16 per k (stride BLOCK = 16 pairs)

    #define PAIR_IJ(p, i, j)                                               \
        int i = (int)((79.0f - sqrtf((float)(6241 - 8 * (p)))) * 0.5f);    \
        int _off = (i * (79 - i)) >> 1;                                    \
        if ((p) < _off) { --i; _off = (i * (79 - i)) >> 1; }               \
        else { int _o2 = ((i + 1) * (78 - i)) >> 1;                        \
               if ((p) >= _o2) { ++i; _off = _o2; } }                      \
        int j = i + 1 + ((p) - _off)

    #pragma unroll 8
    for (int k = 0; k < 48; ++k) {               // 48 full strides for every thread
        int idx = tid + k * BLOCK;
        int p = p0 + k * 16;
        PAIR_IJ(p, i, j);
        f32x4 a = sXW4[i * ROW4 + q];
        f32x4 v = sIn4[j * ROW4 + q];
        out4[idx] = a * v;
    }
    {   // tail: threads tid<192 have a 49th element (12480 = 48*256 + 192)
        int idx = tid + 48 * BLOCK;
        if (idx < OUT4) {
            int p = p0 + 48 * 16;
            PAIR_IJ(p, i, j);
            f32x4 a = sXW4[i * ROW4 + q];
            f32x4 v = sIn4[j * ROW4 + q];
            out4[idx] = a * v;
        }
    }
    #undef PAIR_IJ
}

extern "C" void kernel_launch(void* const* d_in, const int* in_sizes, int n_in,
                              void* d_out, int out_size, void* d_ws, size_t ws_size,
                              hipStream_t stream)
{
    const float* in = (const float*)d_in[0];   // [2048, 40, 64] fp32
    const float* w  = (const float*)d_in[1];   // [64, 64] fp32
    float* out = (float*)d_out;                // [2048, 780*64] fp32

    bilinear_fused<<<2048, BLOCK, 0, stream>>>(in, w, out);
}